// Round 2
// baseline (790.114 us; speedup 1.0000x reference)
//
#include <hip/hip_runtime.h>
#include <math.h>

#define B_SIZE 16384
#define J_ENS  10
#define HD     120
#define XROW   248   // LDS row stride in floats: cols 0..127 = a1 (later A2), 128..247 = h (later h_new, then Kvec)

// workspace float offsets
#define OFF_WT1   0                         // [240][512]  (4 col-blocks of 128: r, z, gx_n, gh_n)
#define OFF_WT2   122880                    // [128][128]  (fc2^T, rows>=120 zero)
#define OFF_WT3   139264                    // [128][32]   (fc3^T, k-major)
#define OFF_BIAS  143360                    // [4][128] combined gate biases
#define OFF_A1B   143872                    // [B][120] a1_base
#define OFF_XPRED (143872 + 16384*120)      // [B][8]
#define OFF_INNOV (OFF_XPRED + 16384*8)     // [B][4]
#define OFF_CORR  (OFF_INNOV + 16384*4)     // [J*B][8]

__device__ __forceinline__ float sigm(float x) { return 1.f / (1.f + expf(-x)); }

// ---------------- prep: transpose/pad weights + bake gate biases ----------------
__global__ void prep_kernel(const float* __restrict__ Wih, const float* __restrict__ Whh,
                            const float* __restrict__ bih, const float* __restrict__ bhh,
                            const float* __restrict__ Wfc2, const float* __restrict__ Wfc3,
                            float* __restrict__ ws) {
    int idx = blockIdx.x * 256 + threadIdx.x;
    if (idx < 122880) {                 // WT1 [k=240][c=512]
        int k = idx >> 9, c = idx & 511;
        int cb = c >> 7, n = c & 127;
        float v = 0.f;
        if (n < 120) {
            if (cb == 0)      v = (k < 120) ? Wih[n * 120 + k]         : Whh[n * 120 + (k - 120)];
            else if (cb == 1) v = (k < 120) ? Wih[(120 + n) * 120 + k] : Whh[(120 + n) * 120 + (k - 120)];
            else if (cb == 2) v = (k < 120) ? Wih[(240 + n) * 120 + k] : 0.f;
            else              v = (k >= 120) ? Whh[(240 + n) * 120 + (k - 120)] : 0.f;
        }
        ws[OFF_WT1 + idx] = v;
    } else if (idx < 139264) {          // WT2 [k=128][o=128]
        int i2 = idx - 122880; int k = i2 >> 7, o = i2 & 127;
        ws[idx] = (k < 120) ? Wfc2[o * 120 + k] : 0.f;
    } else if (idx < 143360) {          // WT3 [o=128][v=32]
        int i3 = idx - 139264; int o = i3 >> 5, v = i3 & 31;
        ws[idx] = Wfc3[v * 128 + o];
    } else if (idx < 143872) {          // biases [4][128]
        int i4 = idx - 143360; int g = i4 >> 7, n = i4 & 127;
        float v = 0.f;
        if (n < 120) {
            if (g == 0)      v = bih[n] + bhh[n];
            else if (g == 1) v = bih[120 + n] + bhh[120 + n];
            else if (g == 2) v = bih[240 + n];
            else             v = bhh[240 + n];
        }
        ws[idx] = v;
    }
}

// ---------------- per-b precompute: x_pred, innovation, a1_base ----------------
__global__ void pre_kernel(const float* __restrict__ y_t, const float* __restrict__ xprev,
                           const float* __restrict__ dxprev, const float* __restrict__ F,
                           const float* __restrict__ Hm, const float* __restrict__ W1,
                           const float* __restrict__ b1, float* __restrict__ ws) {
    int b = blockIdx.x * blockDim.x + threadIdx.x;
    if (b >= B_SIZE) return;
    float xf[8], dx[8], xp[8];
#pragma unroll
    for (int t = 0; t < 8; ++t) { xf[t] = xprev[b * 8 + t]; dx[t] = dxprev[b * 8 + t]; }
#pragma unroll
    for (int s = 0; s < 8; ++s) {
        float a = 0.f;
#pragma unroll
        for (int t = 0; t < 8; ++t) a = fmaf(F[s * 8 + t], xf[t], a);
        xp[s] = a;
    }
    float inn[4];
#pragma unroll
    for (int o = 0; o < 4; ++o) {
        float a = 0.f;
#pragma unroll
        for (int s = 0; s < 8; ++s) a = fmaf(Hm[o * 8 + s], xp[s], a);
        inn[o] = y_t[b * 4 + o] - a;
    }
    float nd = 0.f, ni = 0.f;
#pragma unroll
    for (int s = 0; s < 8; ++s) nd = fmaf(dx[s], dx[s], nd);
#pragma unroll
    for (int o = 0; o < 4; ++o) ni = fmaf(inn[o], inn[o], ni);
    nd = fmaxf(sqrtf(nd), 1e-12f);
    ni = fmaxf(sqrtf(ni), 1e-12f);
    float nn[12];
#pragma unroll
    for (int s = 0; s < 8; ++s) nn[s] = dx[s] / nd;
#pragma unroll
    for (int o = 0; o < 4; ++o) nn[8 + o] = inn[o] / ni;
    for (int n = 0; n < 120; ++n) {
        float a = b1[n];
#pragma unroll
        for (int i = 0; i < 12; ++i) a = fmaf(W1[n * 12 + i], nn[i], a);
        ws[OFF_A1B + b * 120 + n] = fmaxf(a, 0.f);
    }
#pragma unroll
    for (int s = 0; s < 8; ++s) ws[OFF_XPRED + b * 8 + s] = xp[s];
#pragma unroll
    for (int o = 0; o < 4; ++o) ws[OFF_INNOV + b * 4 + o] = inn[o];
}

// ---------------- register-tiled GEMM helper: 8 rows x 4 cols per thread ----------------
// Pure fmaf chains: 4 v_fma_f32 per 4 MACs (no mul/add tax).
__device__ __forceinline__ void gemm_k(const float* __restrict__ Xl, int rowb,
                                       const float* __restrict__ W, int ldw,
                                       int k0, int k1, int xc0, float4 acc[8]) {
    for (int k = k0; k < k1; k += 4) {
        const float* wp = W + (size_t)k * ldw;
        float4 w0 = *(const float4*)(wp);
        float4 w1 = *(const float4*)(wp + ldw);
        float4 w2 = *(const float4*)(wp + 2 * ldw);
        float4 w3 = *(const float4*)(wp + 3 * ldw);
        int xc = xc0 + (k - k0);
#pragma unroll
        for (int i = 0; i < 8; ++i) {
            float4 x = *(const float4*)&Xl[(rowb + i) * XROW + xc];
            acc[i].x = fmaf(x.w, w3.x, fmaf(x.z, w2.x, fmaf(x.y, w1.x, fmaf(x.x, w0.x, acc[i].x))));
            acc[i].y = fmaf(x.w, w3.y, fmaf(x.z, w2.y, fmaf(x.y, w1.y, fmaf(x.x, w0.y, acc[i].y))));
            acc[i].z = fmaf(x.w, w3.z, fmaf(x.z, w2.z, fmaf(x.y, w1.z, fmaf(x.x, w0.z, acc[i].z))));
            acc[i].w = fmaf(x.w, w3.w, fmaf(x.z, w2.w, fmaf(x.y, w1.w, fmaf(x.x, w0.w, acc[i].w))));
        }
    }
}

// ---------------- main fused kernel: 64 rows (= one j, 64 consecutive b) per block ----------------
__launch_bounds__(256, 2)
__global__ void main_kernel(const float* __restrict__ hprev, const float* __restrict__ u1,
                            const float* __restrict__ u2, const float* __restrict__ bfc2,
                            const float* __restrict__ bfc3, const float* __restrict__ pl1,
                            const float* __restrict__ pl2, float* __restrict__ ws) {
    __shared__ float Xl[64 * XROW];
    const float* WT1 = ws + OFF_WT1;
    const float* WT2 = ws + OFF_WT2;
    const float* WT3 = ws + OFF_WT3;
    const float* BI  = ws + OFF_BIAS;
    const float* a1b = ws + OFF_A1B;
    const float* inv_ = ws + OFF_INNOV;
    float* corr = ws + OFF_CORR;

    const int t  = threadIdx.x;
    const int r0 = blockIdx.x * 64;
    const int b0 = r0 & (B_SIZE - 1);

    const float p1 = sigm(pl1[0]);
    const float i1 = 1.f / (1.f - p1);
    const float p2 = sigm(pl2[0]);
    const float i2 = 1.f / (1.f - p2);

    // ---- stage X = [a1_masked | h_prev] ----
    for (int idx = t; idx < 1920; idx += 256) {
        int m = idx / 30, q = idx % 30;
        float4 uu = *(const float4*)&u1[(r0 + m) * 120 + q * 4];
        float4 ab = *(const float4*)&a1b[(b0 + m) * 120 + q * 4];
        float4 hh = *(const float4*)&hprev[(r0 + m) * 120 + q * 4];
        float4 a;
        a.x = (uu.x >= p1) ? ab.x * i1 : 0.f;
        a.y = (uu.y >= p1) ? ab.y * i1 : 0.f;
        a.z = (uu.z >= p1) ? ab.z * i1 : 0.f;
        a.w = (uu.w >= p1) ? ab.w * i1 : 0.f;
        *(float4*)&Xl[m * XROW + q * 4]       = a;
        *(float4*)&Xl[m * XROW + 128 + q * 4] = hh;
    }
    __syncthreads();

    const int tm = t >> 5, tn = t & 31;
    const int rowb = tm * 8;

    // ---- phase 1: gates ----
    float4 ra[8], za[8], xa[8], ga[8];
#pragma unroll
    for (int i = 0; i < 8; ++i) ra[i] = za[i] = xa[i] = ga[i] = make_float4(0.f, 0.f, 0.f, 0.f);
    gemm_k(Xl, rowb, WT1 + tn * 4,       512, 0,   120, 0,   ra);
    gemm_k(Xl, rowb, WT1 + tn * 4,       512, 120, 240, 128, ra);
    gemm_k(Xl, rowb, WT1 + 128 + tn * 4, 512, 0,   120, 0,   za);
    gemm_k(Xl, rowb, WT1 + 128 + tn * 4, 512, 120, 240, 128, za);
    gemm_k(Xl, rowb, WT1 + 256 + tn * 4, 512, 0,   120, 0,   xa);
    gemm_k(Xl, rowb, WT1 + 384 + tn * 4, 512, 120, 240, 128, ga);
    __syncthreads();   // all cross-thread reads of X done

    if (tn < 30) {     // cols tn*4..tn*4+3 are real neurons (<120)
        float4 br = *(const float4*)&BI[tn * 4];
        float4 bz = *(const float4*)&BI[128 + tn * 4];
        float4 bx = *(const float4*)&BI[256 + tn * 4];
        float4 bg = *(const float4*)&BI[384 + tn * 4];
#pragma unroll
        for (int i = 0; i < 8; ++i) {
            float4 h4 = *(const float4*)&Xl[(rowb + i) * XROW + 128 + tn * 4];
            float4 hn;
            {
                float r = sigm(ra[i].x + br.x);
                float z = sigm(za[i].x + bz.x);
                float n = tanhf(xa[i].x + bx.x + r * (ga[i].x + bg.x));
                hn.x = (1.f - z) * n + z * h4.x;
            }
            {
                float r = sigm(ra[i].y + br.y);
                float z = sigm(za[i].y + bz.y);
                float n = tanhf(xa[i].y + bx.y + r * (ga[i].y + bg.y));
                hn.y = (1.f - z) * n + z * h4.y;
            }
            {
                float r = sigm(ra[i].z + br.z);
                float z = sigm(za[i].z + bz.z);
                float n = tanhf(xa[i].z + bx.z + r * (ga[i].z + bg.z));
                hn.z = (1.f - z) * n + z * h4.z;
            }
            {
                float r = sigm(ra[i].w + br.w);
                float z = sigm(za[i].w + bz.w);
                float n = tanhf(xa[i].w + bx.w + r * (ga[i].w + bg.w));
                hn.w = (1.f - z) * n + z * h4.w;
            }
            *(float4*)&Xl[(rowb + i) * XROW + 128 + tn * 4] = hn;
        }
    }
    __syncthreads();   // h_new visible

    // ---- phase 2: fc2 + relu + dropout -> A2 into cols 0..127 ----
    float4 a2[8];
#pragma unroll
    for (int i = 0; i < 8; ++i) a2[i] = make_float4(0.f, 0.f, 0.f, 0.f);
    gemm_k(Xl, rowb, WT2 + tn * 4, 128, 0, 120, 128, a2);
    {
        float4 bf = *(const float4*)&bfc2[tn * 4];
#pragma unroll
        for (int i = 0; i < 8; ++i) {
            float4 uu = *(const float4*)&u2[(r0 + rowb + i) * 128 + tn * 4];
            float4 v;
            v.x = fmaxf(a2[i].x + bf.x, 0.f) * ((uu.x >= p2) ? i2 : 0.f);
            v.y = fmaxf(a2[i].y + bf.y, 0.f) * ((uu.y >= p2) ? i2 : 0.f);
            v.z = fmaxf(a2[i].z + bf.z, 0.f) * ((uu.z >= p2) ? i2 : 0.f);
            v.w = fmaxf(a2[i].w + bf.w, 0.f) * ((uu.w >= p2) ? i2 : 0.f);
            *(float4*)&Xl[(rowb + i) * XROW + tn * 4] = v;   // overwrite a1 region (no longer read)
        }
    }
    __syncthreads();   // A2 visible

    // ---- phase 3: fc3 -> Kvec (col 128+v), then corr ----
    {
        float a3[8];
#pragma unroll
        for (int i = 0; i < 8; ++i) a3[i] = 0.f;
        for (int k = 0; k < 128; k += 4) {
            float w0 = WT3[k * 32 + tn];
            float w1 = WT3[(k + 1) * 32 + tn];
            float w2 = WT3[(k + 2) * 32 + tn];
            float w3 = WT3[(k + 3) * 32 + tn];
#pragma unroll
            for (int i = 0; i < 8; ++i) {
                float4 x = *(const float4*)&Xl[(rowb + i) * XROW + k];
                a3[i] = fmaf(x.w, w3, fmaf(x.z, w2, fmaf(x.y, w1, fmaf(x.x, w0, a3[i]))));
            }
        }
        float bv = bfc3[tn];
#pragma unroll
        for (int i = 0; i < 8; ++i)
            Xl[(rowb + i) * XROW + 128 + tn] = a3[i] + bv;   // Kvec over h_new region (done)
    }
    __syncthreads();

    for (int idx = t; idx < 512; idx += 256) {
        int m = idx >> 3, s = idx & 7;
        const float* kv = &Xl[m * XROW + 128 + s * 4];
        float4 iv = *(const float4*)&inv_[(b0 + m) * 4];
        corr[(r0 + m) * 8 + s] = fmaf(kv[3], iv.w, fmaf(kv[2], iv.z, fmaf(kv[1], iv.y, kv[0] * iv.x)));
    }
}

// ---------------- per-b reduction over J: mean + covariance ----------------
__global__ void reduce_kernel(const float* __restrict__ ws, float* __restrict__ out) {
    int b = blockIdx.x * 256 + threadIdx.x;
    if (b >= B_SIZE) return;
    const float* corr  = ws + OFF_CORR;
    const float* xpred = ws + OFF_XPRED;
    float S[8];
    float SS[64];
#pragma unroll
    for (int s = 0; s < 8; ++s) S[s] = 0.f;
#pragma unroll
    for (int q = 0; q < 64; ++q) SS[q] = 0.f;
    for (int j = 0; j < J_ENS; ++j) {
        float c[8];
        float4 c0 = *(const float4*)&corr[(j * B_SIZE + b) * 8];
        float4 c1 = *(const float4*)&corr[(j * B_SIZE + b) * 8 + 4];
        c[0] = c0.x; c[1] = c0.y; c[2] = c0.z; c[3] = c0.w;
        c[4] = c1.x; c[5] = c1.y; c[6] = c1.z; c[7] = c1.w;
#pragma unroll
        for (int s = 0; s < 8; ++s) S[s] += c[s];
#pragma unroll
        for (int s = 0; s < 8; ++s)
#pragma unroll
            for (int tt = 0; tt < 8; ++tt) SS[s * 8 + tt] = fmaf(c[s], c[tt], SS[s * 8 + tt]);
    }
    const float invJ = 1.f / (float)J_ENS;
    float mc[8];
#pragma unroll
    for (int s = 0; s < 8; ++s) {
        mc[s] = S[s] * invJ;
        out[b * 8 + s] = xpred[b * 8 + s] + mc[s];
    }
#pragma unroll
    for (int s = 0; s < 8; ++s)
#pragma unroll
        for (int tt = 0; tt < 8; ++tt)
            out[131072 + b * 64 + s * 8 + tt] = SS[s * 8 + tt] * invJ - mc[s] * mc[tt];
}

// ---------------- regularizer scalar ----------------
__global__ void reg_kernel(const float* __restrict__ W1, const float* __restrict__ W2,
                           const float* __restrict__ pl1, const float* __restrict__ pl2,
                           float* __restrict__ out) {
    __shared__ float red[256];
    int t = threadIdx.x;
    float s1 = 0.f, s2 = 0.f;
    for (int i = t; i < 1440; i += 256)  { float v = W1[i]; s1 = fmaf(v, v, s1); }
    for (int i = t; i < 15360; i += 256) { float v = W2[i]; s2 = fmaf(v, v, s2); }
    red[t] = s1; __syncthreads();
    for (int s = 128; s > 0; s >>= 1) { if (t < s) red[t] += red[t + s]; __syncthreads(); }
    float r1 = red[0]; __syncthreads();
    red[t] = s2; __syncthreads();
    for (int s = 128; s > 0; s >>= 1) { if (t < s) red[t] += red[t + s]; __syncthreads(); }
    if (t == 0) {
        float p1 = sigm(pl1[0]), p2 = sigm(pl2[0]);
        float e1 = p1 * logf(p1) + (1.f - p1) * logf(1.f - p1);
        float e2 = p2 * logf(p2) + (1.f - p2) * logf(1.f - p2);
        out[1179648] = r1 / (1.f - p1) + e1 + red[0] / (1.f - p2) + e2;
    }
}

extern "C" void kernel_launch(void* const* d_in, const int* in_sizes, int n_in,
                              void* d_out, int out_size, void* d_ws, size_t ws_size,
                              hipStream_t stream) {
    const float* y_t   = (const float*)d_in[0];
    const float* xfp   = (const float*)d_in[1];
    const float* dxp   = (const float*)d_in[2];
    const float* hprev = (const float*)d_in[3];
    const float* F     = (const float*)d_in[4];
    const float* Hm    = (const float*)d_in[5];
    const float* W1    = (const float*)d_in[6];
    const float* b1    = (const float*)d_in[7];
    const float* Wih   = (const float*)d_in[8];
    const float* Whh   = (const float*)d_in[9];
    const float* bih   = (const float*)d_in[10];
    const float* bhh   = (const float*)d_in[11];
    const float* W2    = (const float*)d_in[12];
    const float* b2    = (const float*)d_in[13];
    const float* W3    = (const float*)d_in[14];
    const float* b3    = (const float*)d_in[15];
    const float* pl1   = (const float*)d_in[16];
    const float* pl2   = (const float*)d_in[17];
    const float* u1    = (const float*)d_in[18];
    const float* u2    = (const float*)d_in[19];
    float* out = (float*)d_out;
    float* ws  = (float*)d_ws;

    prep_kernel<<<dim3(562), dim3(256), 0, stream>>>(Wih, Whh, bih, bhh, W2, W3, ws);
    pre_kernel<<<dim3(64), dim3(256), 0, stream>>>(y_t, xfp, dxp, F, Hm, W1, b1, ws);
    main_kernel<<<dim3(2560), dim3(256), 0, stream>>>(hprev, u1, u2, b2, b3, pl1, pl2, ws);
    reduce_kernel<<<dim3(64), dim3(256), 0, stream>>>(ws, out);
    reg_kernel<<<dim3(1), dim3(256), 0, stream>>>(W1, W2, pl1, pl2, out);
}

// Round 4
// 415.618 us; speedup vs baseline: 1.9011x; 1.9011x over previous
//
#include <hip/hip_runtime.h>
#include <hip/hip_bf16.h>
#include <math.h>

#define B_SIZE 16384
#define J_ENS  10

// ---- workspace layout ----
// u16-unit offsets (bf16 regions)
#define U_WB1   0           // [512][256] bf16  gate weights [N][K]
#define U_WB2   131072      // [128][128] bf16  fc2 [N][K] (k>=120 zero)
#define U_WB3   147456      // [32][128]  bf16  fc3 [N][K]
#define U_A1S   152576      // [B][120]   bf16  pre-scaled a1 (relu*i1)
// float-unit offsets
#define F_GB    75776       // [4][128] f32 combined gate biases
#define F_XPRED 1059328     // [B][8]  f32
#define F_INNOV 1190400     // [B][4]  f32
#define F_CORR  1255936     // [J*B][8] f32

typedef __attribute__((ext_vector_type(8))) short s16x8;
typedef __attribute__((ext_vector_type(4))) float f32x4;

__device__ __forceinline__ float sigm(float x) { return 1.f / (1.f + expf(-x)); }
__device__ __forceinline__ float fsigm(float x) { return __builtin_amdgcn_rcpf(1.f + __expf(-x)); }
__device__ __forceinline__ float ftanh(float x) {
    float e = __expf(2.f * x);
    return 1.f - 2.f * __builtin_amdgcn_rcpf(e + 1.f);
}
__device__ __forceinline__ unsigned short f2bf(float x) {
    __hip_bfloat16 h = __float2bfloat16(x);
    return __builtin_bit_cast(unsigned short, h);
}

// ---------------- prep: weights -> bf16 [N][K] padded + gate biases ----------------
__global__ void prep_kernel(const float* __restrict__ Wih, const float* __restrict__ Whh,
                            const float* __restrict__ bih, const float* __restrict__ bhh,
                            const float* __restrict__ Wfc2, const float* __restrict__ Wfc3,
                            float* __restrict__ ws) {
    unsigned short* wsu = (unsigned short*)ws;
    int idx = blockIdx.x * 256 + threadIdx.x;
    if (idx < 131072) {                     // WB1 [n=512][k=256]
        int n = idx >> 8, k = idx & 255;
        int cb = n >> 7, nn = n & 127;
        float v = 0.f;
        if (nn < 120) {
            if (cb == 0)      v = (k < 120) ? Wih[nn * 120 + k]         : ((k < 240) ? Whh[nn * 120 + (k - 120)] : 0.f);
            else if (cb == 1) v = (k < 120) ? Wih[(120 + nn) * 120 + k] : ((k < 240) ? Whh[(120 + nn) * 120 + (k - 120)] : 0.f);
            else if (cb == 2) v = (k < 120) ? Wih[(240 + nn) * 120 + k] : 0.f;
            else              v = (k >= 120 && k < 240) ? Whh[(240 + nn) * 120 + (k - 120)] : 0.f;
        }
        wsu[U_WB1 + idx] = f2bf(v);
    } else if (idx < 147456) {              // WB2 [o=128][k=128]
        int i2 = idx - 131072; int o = i2 >> 7, k = i2 & 127;
        wsu[U_WB2 + i2] = f2bf((k < 120) ? Wfc2[o * 120 + k] : 0.f);
    } else if (idx < 151552) {              // WB3 [v=32][k=128] (exact copy)
        int i3 = idx - 147456;
        wsu[U_WB3 + i3] = f2bf(Wfc3[i3]);
    } else if (idx < 152064) {              // gate biases [4][128] f32
        int i4 = idx - 151552; int g = i4 >> 7, n = i4 & 127;
        float v = 0.f;
        if (n < 120) {
            if (g == 0)      v = bih[n] + bhh[n];
            else if (g == 1) v = bih[120 + n] + bhh[120 + n];
            else if (g == 2) v = bih[240 + n];
            else             v = bhh[240 + n];
        }
        ws[F_GB + i4] = v;
    }
}

// ---------------- per-b precompute: x_pred, innovation, pre-scaled a1 (bf16) ----------------
__global__ void pre_kernel(const float* __restrict__ y_t, const float* __restrict__ xprev,
                           const float* __restrict__ dxprev, const float* __restrict__ F,
                           const float* __restrict__ Hm, const float* __restrict__ W1,
                           const float* __restrict__ b1, const float* __restrict__ pl1,
                           float* __restrict__ ws) {
    int b = blockIdx.x * blockDim.x + threadIdx.x;
    if (b >= B_SIZE) return;
    unsigned short* wsu = (unsigned short*)ws;
    float p1 = sigm(pl1[0]);
    float i1 = 1.f / (1.f - p1);
    float xf[8], dx[8], xp[8];
#pragma unroll
    for (int t = 0; t < 8; ++t) { xf[t] = xprev[b * 8 + t]; dx[t] = dxprev[b * 8 + t]; }
#pragma unroll
    for (int s = 0; s < 8; ++s) {
        float a = 0.f;
#pragma unroll
        for (int t = 0; t < 8; ++t) a = fmaf(F[s * 8 + t], xf[t], a);
        xp[s] = a;
    }
    float inn[4];
#pragma unroll
    for (int o = 0; o < 4; ++o) {
        float a = 0.f;
#pragma unroll
        for (int s = 0; s < 8; ++s) a = fmaf(Hm[o * 8 + s], xp[s], a);
        inn[o] = y_t[b * 4 + o] - a;
    }
    float nd = 0.f, ni = 0.f;
#pragma unroll
    for (int s = 0; s < 8; ++s) nd = fmaf(dx[s], dx[s], nd);
#pragma unroll
    for (int o = 0; o < 4; ++o) ni = fmaf(inn[o], inn[o], ni);
    nd = fmaxf(sqrtf(nd), 1e-12f);
    ni = fmaxf(sqrtf(ni), 1e-12f);
    float nn[12];
#pragma unroll
    for (int s = 0; s < 8; ++s) nn[s] = dx[s] / nd;
#pragma unroll
    for (int o = 0; o < 4; ++o) nn[8 + o] = inn[o] / ni;
    for (int n = 0; n < 120; ++n) {
        float a = b1[n];
#pragma unroll
        for (int i = 0; i < 12; ++i) a = fmaf(W1[n * 12 + i], nn[i], a);
        wsu[U_A1S + b * 120 + n] = f2bf(fmaxf(a, 0.f) * i1);
    }
#pragma unroll
    for (int s = 0; s < 8; ++s) ws[F_XPRED + b * 8 + s] = xp[s];
#pragma unroll
    for (int o = 0; o < 4; ++o) ws[F_INNOV + b * 4 + o] = inn[o];
}

// ---------------- main fused MFMA kernel: 64 rows per block, 4 waves ----------------
__launch_bounds__(256, 2)
__global__ void main_kernel(const float* __restrict__ hprev, const float* __restrict__ u1,
                            const float* __restrict__ u2, const float* __restrict__ b2,
                            const float* __restrict__ b3, const float* __restrict__ pl1,
                            const float* __restrict__ pl2, float* __restrict__ ws) {
    __shared__ unsigned short Xl[64 * 264];   // [64][264] bf16: 0..119 a1, 120..239 h, 240..255 zero-pad
    __shared__ unsigned short Hn[64 * 136];   // [64][136] bf16: h_new, cols 120..127 zero
    __shared__ unsigned short A2l[64 * 136];  // [64][136] bf16: fc2 activations
    __shared__ float Kvl[64 * 40];            // [64][40] f32: Kvec (32 cols)

    const unsigned short* WB1p = (const unsigned short*)ws + U_WB1;
    const unsigned short* WB2p = (const unsigned short*)ws + U_WB2;
    const unsigned short* WB3p = (const unsigned short*)ws + U_WB3;
    const unsigned short* a1s  = (const unsigned short*)ws + U_A1S;
    const float* GB = ws + F_GB;

    const int t  = threadIdx.x;
    const int r0 = blockIdx.x * 64;
    const int b0 = r0 & (B_SIZE - 1);

    const float p1 = sigm(pl1[0]);
    const float p2 = sigm(pl2[0]);
    const float i2 = 1.f / (1.f - p2);

    // ---- stage X = [a1_masked | h_prev] as bf16 ----
    for (int idx = t; idx < 1920; idx += 256) {
        int m = idx / 30, q = (idx % 30) * 4;
        float4 uu = *(const float4*)&u1[(size_t)(r0 + m) * 120 + q];
        ushort4 aa = *(const ushort4*)&a1s[(b0 + m) * 120 + q];
        ushort4 xv;
        xv.x = (uu.x >= p1) ? aa.x : (unsigned short)0;
        xv.y = (uu.y >= p1) ? aa.y : (unsigned short)0;
        xv.z = (uu.z >= p1) ? aa.z : (unsigned short)0;
        xv.w = (uu.w >= p1) ? aa.w : (unsigned short)0;
        *(ushort4*)&Xl[m * 264 + q] = xv;
        float4 hh = *(const float4*)&hprev[(size_t)(r0 + m) * 120 + q];
        ushort4 hv;
        hv.x = f2bf(hh.x); hv.y = f2bf(hh.y); hv.z = f2bf(hh.z); hv.w = f2bf(hh.w);
        *(ushort4*)&Xl[m * 264 + 120 + q] = hv;
    }
    // zero pads: Xl cols 240..255, Hn cols 120..127
    for (int idx = t; idx < 512; idx += 256) {
        int m = idx >> 3, c = 240 + ((idx & 7) << 1);
        ushort2 z; z.x = 0; z.y = 0;
        *(ushort2*)&Xl[m * 264 + c] = z;
    }
    {
        int m = t >> 2, c = 120 + ((t & 3) << 1);
        ushort2 z; z.x = 0; z.y = 0;
        *(ushort2*)&Hn[m * 136 + c] = z;
    }
    __syncthreads();

    const int wv = t >> 6;          // wave 0..3
    const int ln = t & 63;
    const int lr = ln & 15;         // A-row / B-col within frag
    const int kg = (ln >> 4) * 8;   // k-offset within frag
    const int rbase = (ln >> 4) * 4;

    // ---- phase 1: gates GEMM [64x256]x[256x512]; wave wv owns cols wv*32..wv*32+31 of each gate ----
    f32x4 acc[32];
#pragma unroll
    for (int i = 0; i < 32; ++i) acc[i] = (f32x4){0.f, 0.f, 0.f, 0.f};
#pragma unroll
    for (int ks = 0; ks < 8; ++ks) {
        s16x8 af[4];
#pragma unroll
        for (int mf = 0; mf < 4; ++mf)
            af[mf] = *(const s16x8*)&Xl[(mf * 16 + lr) * 264 + ks * 32 + kg];
#pragma unroll
        for (int g = 0; g < 4; ++g) {
#pragma unroll
            for (int cf = 0; cf < 2; ++cf) {
                s16x8 bf = *(const s16x8*)&WB1p[(size_t)(g * 128 + wv * 32 + cf * 16 + lr) * 256 + ks * 32 + kg];
#pragma unroll
                for (int mf = 0; mf < 4; ++mf)
                    acc[mf * 8 + g * 2 + cf] =
                        __builtin_amdgcn_mfma_f32_16x16x32_bf16(af[mf], bf, acc[mf * 8 + g * 2 + cf], 0, 0, 0);
            }
        }
    }

    // ---- GRU nonlinearity epilogue -> Hn (bf16) ----
#pragma unroll
    for (int cf = 0; cf < 2; ++cf) {
        int c = wv * 32 + cf * 16 + lr;
        if (c < 120) {
            float br = GB[c], bz = GB[128 + c], bx = GB[256 + c], bg = GB[384 + c];
#pragma unroll
            for (int mf = 0; mf < 4; ++mf) {
                f32x4 rA = acc[mf * 8 + 0 + cf];
                f32x4 zA = acc[mf * 8 + 2 + cf];
                f32x4 xA = acc[mf * 8 + 4 + cf];
                f32x4 gA = acc[mf * 8 + 6 + cf];
#pragma unroll
                for (int rr = 0; rr < 4; ++rr) {
                    int row = mf * 16 + rbase + rr;
                    float hp = hprev[(size_t)(r0 + row) * 120 + c];
                    float r = fsigm(rA[rr] + br);
                    float z = fsigm(zA[rr] + bz);
                    float n = ftanh(xA[rr] + bx + r * (gA[rr] + bg));
                    Hn[row * 136 + c] = f2bf((1.f - z) * n + z * hp);
                }
            }
        }
    }
    __syncthreads();

    // ---- phase 2: fc2 [64x128]x[128x128] + relu + dropout -> A2l ----
    f32x4 acc2[8];
#pragma unroll
    for (int i = 0; i < 8; ++i) acc2[i] = (f32x4){0.f, 0.f, 0.f, 0.f};
#pragma unroll
    for (int ks = 0; ks < 4; ++ks) {
        s16x8 af[4];
#pragma unroll
        for (int mf = 0; mf < 4; ++mf)
            af[mf] = *(const s16x8*)&Hn[(mf * 16 + lr) * 136 + ks * 32 + kg];
#pragma unroll
        for (int cf = 0; cf < 2; ++cf) {
            s16x8 bf = *(const s16x8*)&WB2p[(wv * 32 + cf * 16 + lr) * 128 + ks * 32 + kg];
#pragma unroll
            for (int mf = 0; mf < 4; ++mf)
                acc2[mf * 2 + cf] =
                    __builtin_amdgcn_mfma_f32_16x16x32_bf16(af[mf], bf, acc2[mf * 2 + cf], 0, 0, 0);
        }
    }
#pragma unroll
    for (int cf = 0; cf < 2; ++cf) {
        int c = wv * 32 + cf * 16 + lr;
        float bb = b2[c];
#pragma unroll
        for (int mf = 0; mf < 4; ++mf) {
#pragma unroll
            for (int rr = 0; rr < 4; ++rr) {
                int row = mf * 16 + rbase + rr;
                float uu = u2[(size_t)(r0 + row) * 128 + c];
                float v = fmaxf(acc2[mf * 2 + cf][rr] + bb, 0.f);
                v = (uu >= p2) ? v * i2 : 0.f;
                A2l[row * 136 + c] = f2bf(v);
            }
        }
    }
    __syncthreads();

    // ---- phase 3: fc3 [64x128]x[128x32] -> Kvl; wave wv owns rows wv*16..wv*16+15 ----
    {
        const int m0 = wv * 16;
        f32x4 a3[2];
#pragma unroll
        for (int i = 0; i < 2; ++i) a3[i] = (f32x4){0.f, 0.f, 0.f, 0.f};
#pragma unroll
        for (int ks = 0; ks < 4; ++ks) {
            s16x8 a = *(const s16x8*)&A2l[(m0 + lr) * 136 + ks * 32 + kg];
#pragma unroll
            for (int nf = 0; nf < 2; ++nf) {
                s16x8 bf = *(const s16x8*)&WB3p[(nf * 16 + lr) * 128 + ks * 32 + kg];
                a3[nf] = __builtin_amdgcn_mfma_f32_16x16x32_bf16(a, bf, a3[nf], 0, 0, 0);
            }
        }
#pragma unroll
        for (int nf = 0; nf < 2; ++nf) {
            int c = nf * 16 + lr;
            float bb = b3[c];
#pragma unroll
            for (int rr = 0; rr < 4; ++rr) {
                int row = m0 + rbase + rr;
                Kvl[row * 40 + c] = a3[nf][rr] + bb;
            }
        }
    }
    __syncthreads();

    // ---- corr = K . innovation ----
    for (int idx = t; idx < 512; idx += 256) {
        int m = idx >> 3, s = idx & 7;
        float4 iv = *(const float4*)&ws[F_INNOV + (b0 + m) * 4];
        const float* kv = &Kvl[m * 40 + s * 4];
        ws[F_CORR + (size_t)(r0 + m) * 8 + s] =
            fmaf(kv[3], iv.w, fmaf(kv[2], iv.z, fmaf(kv[1], iv.y, kv[0] * iv.x)));
    }
}

// ---------------- per-b reduction over J: mean + covariance ----------------
__global__ void reduce_kernel(const float* __restrict__ ws, float* __restrict__ out) {
    int b = blockIdx.x * 256 + threadIdx.x;
    if (b >= B_SIZE) return;
    const float* corr  = ws + F_CORR;
    const float* xpred = ws + F_XPRED;
    float S[8];
    float SS[64];
#pragma unroll
    for (int s = 0; s < 8; ++s) S[s] = 0.f;
#pragma unroll
    for (int q = 0; q < 64; ++q) SS[q] = 0.f;
    for (int j = 0; j < J_ENS; ++j) {
        float c[8];
        float4 c0 = *(const float4*)&corr[(size_t)(j * B_SIZE + b) * 8];
        float4 c1 = *(const float4*)&corr[(size_t)(j * B_SIZE + b) * 8 + 4];
        c[0] = c0.x; c[1] = c0.y; c[2] = c0.z; c[3] = c0.w;
        c[4] = c1.x; c[5] = c1.y; c[6] = c1.z; c[7] = c1.w;
#pragma unroll
        for (int s = 0; s < 8; ++s) S[s] += c[s];
#pragma unroll
        for (int s = 0; s < 8; ++s)
#pragma unroll
            for (int tt = 0; tt < 8; ++tt) SS[s * 8 + tt] = fmaf(c[s], c[tt], SS[s * 8 + tt]);
    }
    const float invJ = 1.f / (float)J_ENS;
    float mc[8];
#pragma unroll
    for (int s = 0; s < 8; ++s) {
        mc[s] = S[s] * invJ;
        out[b * 8 + s] = xpred[b * 8 + s] + mc[s];
    }
#pragma unroll
    for (int s = 0; s < 8; ++s)
#pragma unroll
        for (int tt = 0; tt < 8; ++tt)
            out[131072 + b * 64 + s * 8 + tt] = SS[s * 8 + tt] * invJ - mc[s] * mc[tt];
}

// ---------------- regularizer scalar ----------------
__global__ void reg_kernel(const float* __restrict__ W1, const float* __restrict__ W2,
                           const float* __restrict__ pl1, const float* __restrict__ pl2,
                           float* __restrict__ out) {
    __shared__ float red[256];
    int t = threadIdx.x;
    float s1 = 0.f, s2 = 0.f;
    for (int i = t; i < 1440; i += 256)  { float v = W1[i]; s1 = fmaf(v, v, s1); }
    for (int i = t; i < 15360; i += 256) { float v = W2[i]; s2 = fmaf(v, v, s2); }
    red[t] = s1; __syncthreads();
    for (int s = 128; s > 0; s >>= 1) { if (t < s) red[t] += red[t + s]; __syncthreads(); }
    float r1 = red[0]; __syncthreads();
    red[t] = s2; __syncthreads();
    for (int s = 128; s > 0; s >>= 1) { if (t < s) red[t] += red[t + s]; __syncthreads(); }
    if (t == 0) {
        float p1 = sigm(pl1[0]), p2 = sigm(pl2[0]);
        float e1 = p1 * logf(p1) + (1.f - p1) * logf(1.f - p1);
        float e2 = p2 * logf(p2) + (1.f - p2) * logf(1.f - p2);
        out[1179648] = r1 / (1.f - p1) + e1 + red[0] / (1.f - p2) + e2;
    }
}

extern "C" void kernel_launch(void* const* d_in, const int* in_sizes, int n_in,
                              void* d_out, int out_size, void* d_ws, size_t ws_size,
                              hipStream_t stream) {
    const float* y_t   = (const float*)d_in[0];
    const float* xfp   = (const float*)d_in[1];
    const float* dxp   = (const float*)d_in[2];
    const float* hprev = (const float*)d_in[3];
    const float* F     = (const float*)d_in[4];
    const float* Hm    = (const float*)d_in[5];
    const float* W1    = (const float*)d_in[6];
    const float* b1    = (const float*)d_in[7];
    const float* Wih   = (const float*)d_in[8];
    const float* Whh   = (const float*)d_in[9];
    const float* bih   = (const float*)d_in[10];
    const float* bhh   = (const float*)d_in[11];
    const float* W2    = (const float*)d_in[12];
    const float* b2    = (const float*)d_in[13];
    const float* W3    = (const float*)d_in[14];
    const float* b3    = (const float*)d_in[15];
    const float* pl1   = (const float*)d_in[16];
    const float* pl2   = (const float*)d_in[17];
    const float* u1    = (const float*)d_in[18];
    const float* u2    = (const float*)d_in[19];
    float* out = (float*)d_out;
    float* ws  = (float*)d_ws;

    prep_kernel<<<dim3(594), dim3(256), 0, stream>>>(Wih, Whh, bih, bhh, W2, W3, ws);
    pre_kernel<<<dim3(64), dim3(256), 0, stream>>>(y_t, xfp, dxp, F, Hm, W1, b1, pl1, ws);
    main_kernel<<<dim3(2560), dim3(256), 0, stream>>>(hprev, u1, u2, b2, b3, pl1, pl2, ws);
    reduce_kernel<<<dim3(64), dim3(256), 0, stream>>>(ws, out);
    reg_kernel<<<dim3(1), dim3(256), 0, stream>>>(W1, W2, pl1, pl2, out);
}